// Round 5
// baseline (211.416 us; speedup 1.0000x reference)
//
#include <hip/hip_runtime.h>
#include <math.h>

#define HH 256
#define NN 64
#define LL 4096
#define BB 8

// ws layout (floats):
//   u_ws (float [B][H][L])     @ 327680    (8388608)
//   g    (float [B][H])        @ 10813440  (2048)
//   Krev (float [H][L])        @ 10815488  (1048576)   K[h, L-1-l]

// k1: blocks [0,512) = embedding gather+transpose (unchanged, proven);
//     blocks [512,768) = K-materialization, one block per h:
//       K[h,l] = Re( sum_n w[h,n] * dA[h,n]^l ),  w = 2*C0*dB
//     wave w owns n in [8w,8w+8); lane owns l = j*64+lane, j=0..63.
//     Per n: dA^lane by 6-bit square-multiply, then 64-step geometric
//     recurrence (*dA^64) accumulating Re into kacc[64] regs; waves merge
//     via LDS atomicAdd (ds_add_f32); K stored reversed for the conv.
__global__ __launch_bounds__(512) void frontend_kernel(
    const int* __restrict__ ids, const float* __restrict__ emb,
    const float* __restrict__ log_dt, const float* __restrict__ A_log_re,
    const float* __restrict__ A_im, const float* __restrict__ B_re,
    const float* __restrict__ B_im, const float* __restrict__ C_re,
    const float* __restrict__ C_im,
    float* __restrict__ u_ws, float* __restrict__ Krev) {
    __shared__ union {
        struct { int ids_s[64]; float tb[2][64][65]; } a;      // 33.5 KB
        struct { float4 cs4[NN]; float2 cs2[NN]; float Kbuf[LL]; } k; // 17.5 KB
    } sm;
    int t = threadIdx.x;
    if (blockIdx.x < BB * 64) {
        // ---------------- gather + transpose ----------------
        int b = blockIdx.x >> 6;
        int tile = blockIdx.x & 63;
        int w = t >> 6;           // wave id 0..7
        int lane = t & 63;
        int rq = lane >> 4;       // row-within-quad 0..3
        int k = lane & 15;        // float4 column 0..15
        if (t < 64) sm.a.ids_s[t] = ids[b * LL + tile * 64 + t];
        __syncthreads();
        {
            int r0 = w * 8 + rq;
            float4 v0 = *(const float4*)(emb + (long)sm.a.ids_s[r0] * HH + 4 * k);
            float4 v1 = *(const float4*)(emb + (long)sm.a.ids_s[r0 + 4] * HH + 4 * k);
            sm.a.tb[0][r0][4 * k + 0] = v0.x;
            sm.a.tb[0][r0][4 * k + 1] = v0.y;
            sm.a.tb[0][r0][4 * k + 2] = v0.z;
            sm.a.tb[0][r0][4 * k + 3] = v0.w;
            sm.a.tb[0][r0 + 4][4 * k + 0] = v1.x;
            sm.a.tb[0][r0 + 4][4 * k + 1] = v1.y;
            sm.a.tb[0][r0 + 4][4 * k + 2] = v1.z;
            sm.a.tb[0][r0 + 4][4 * k + 3] = v1.w;
        }
        __syncthreads();
        #pragma unroll
        for (int c4 = 0; c4 < 4; ++c4) {
            int cur = c4 & 1;
            float4 v0, v1;
            if (c4 < 3) {
                int r0 = w * 8 + rq;
                v0 = *(const float4*)(emb + (long)sm.a.ids_s[r0] * HH +
                                      (c4 + 1) * 64 + 4 * k);
                v1 = *(const float4*)(emb + (long)sm.a.ids_s[r0 + 4] * HH +
                                      (c4 + 1) * 64 + 4 * k);
            }
            #pragma unroll
            for (int it = 0; it < 2; ++it) {
                int hq = w * 8 + it * 4 + rq;
                int s0 = 4 * k;
                float4 o;
                o.x = sm.a.tb[cur][s0 + 0][hq];
                o.y = sm.a.tb[cur][s0 + 1][hq];
                o.z = sm.a.tb[cur][s0 + 2][hq];
                o.w = sm.a.tb[cur][s0 + 3][hq];
                *(float4*)(u_ws + ((long)(b * HH + c4 * 64 + hq)) * LL +
                           tile * 64 + s0) = o;
            }
            if (c4 < 3) {
                int r0 = w * 8 + rq;
                sm.a.tb[cur ^ 1][r0][4 * k + 0] = v0.x;
                sm.a.tb[cur ^ 1][r0][4 * k + 1] = v0.y;
                sm.a.tb[cur ^ 1][r0][4 * k + 2] = v0.z;
                sm.a.tb[cur ^ 1][r0][4 * k + 3] = v0.w;
                sm.a.tb[cur ^ 1][r0 + 4][4 * k + 0] = v1.x;
                sm.a.tb[cur ^ 1][r0 + 4][4 * k + 1] = v1.y;
                sm.a.tb[cur ^ 1][r0 + 4][4 * k + 2] = v1.z;
                sm.a.tb[cur ^ 1][r0 + 4][4 * k + 3] = v1.w;
            }
            __syncthreads();
        }
    } else {
        // ---------------- K-materialization (one block per h) ----------------
        int h = blockIdx.x - BB * 64;
        int w = t >> 6, lane = t & 63;
        #pragma unroll
        for (int i = 0; i < 8; ++i) sm.k.Kbuf[i * 512 + t] = 0.0f;
        if (t < NN) {
            int n = t;
            int idx = h * NN + n;
            float dt = expf(log_dt[h]);
            float Are = -expf(A_log_re[idx]);
            float Aim = A_im[idx];
            float ea = expf(dt * Are);
            float sn, cs;
            sincosf(dt * Aim, &sn, &cs);
            float dAre = ea * cs, dAim = ea * sn;
            float numre = dAre - 1.0f, numim = dAim;
            float den = Are * Are + Aim * Aim;
            float qre = (numre * Are + numim * Aim) / den;
            float qim = (numim * Are - numre * Aim) / den;
            float bre = B_re[idx], bim = B_im[idx];
            float dBre = bre * qre - bim * qim;
            float dBim = bre * qim + bim * qre;
            float cre = C_re[idx], cim = C_im[idx];
            float wre = 2.0f * (cre * dBre - cim * dBim);
            float wim = 2.0f * (cre * dBim + cim * dBre);
            // dA64 = dA^64
            float pr = dAre, pi = dAim;
            #pragma unroll
            for (int kq = 0; kq < 6; ++kq) {
                float nr = pr * pr - pi * pi;
                pi = 2.0f * pr * pi; pr = nr;
            }
            sm.k.cs4[n] = make_float4(dAre, dAim, wre, wim);
            sm.k.cs2[n] = make_float2(pr, pi);
        }
        __syncthreads();
        float kacc[64];
        #pragma unroll
        for (int j = 0; j < 64; ++j) kacc[j] = 0.0f;
        #pragma unroll 2
        for (int nn = 0; nn < 8; ++nn) {
            int n = w * 8 + nn;
            float4 c4 = sm.k.cs4[n];     // (dAre, dAim, wre, wim) broadcast
            float2 c2 = sm.k.cs2[n];     // dA^64
            // p = dA^lane via 6-bit square-and-multiply
            float pr = 1.0f, pi = 0.0f, br = c4.x, bi = c4.y;
            #pragma unroll
            for (int bit = 0; bit < 6; ++bit) {
                bool on = (lane >> bit) & 1;
                float mr = on ? br : 1.0f;
                float mi = on ? bi : 0.0f;
                float tr = pr * mr - pi * mi;
                pi = pr * mi + pi * mr; pr = tr;
                float t2 = br * br - bi * bi;
                bi = 2.0f * br * bi; br = t2;
            }
            // v = w * dA^lane; then 64 steps of *dA^64, accumulating Re
            float vr = c4.z * pr - c4.w * pi;
            float vi = c4.z * pi + c4.w * pr;
            #pragma unroll
            for (int j = 0; j < 64; ++j) {
                kacc[j] += vr;
                float tr = vr * c2.x - vi * c2.y;
                vi = vr * c2.y + vi * c2.x; vr = tr;
            }
        }
        #pragma unroll
        for (int j = 0; j < 64; ++j)
            atomicAdd(&sm.k.Kbuf[j * 64 + lane], kacc[j]);
        __syncthreads();
        #pragma unroll
        for (int i = 0; i < 8; ++i) {
            int tp = i * 512 + t;
            Krev[h * LL + tp] = sm.k.Kbuf[LL - 1 - tp];   // store reversed
        }
    }
}

// k2: conv -- y[b,h] = sum_t u[t]*Krev[t] + D[h]*u[L-1], GELU -> g.
// Pure streaming dot: 2048 blocks x 256 threads, 16 floats per thread.
__global__ __launch_bounds__(256) void conv_kernel(
    const float* __restrict__ u_ws, const float* __restrict__ Krev,
    const float* __restrict__ Dv, float* __restrict__ g) {
    __shared__ float partial[4];
    int t = threadIdx.x;
    int bh = blockIdx.x;
    int h = bh & (HH - 1);
    const float4* up = (const float4*)(u_ws + (long)bh * LL);
    const float4* kp = (const float4*)(Krev + h * LL);
    float acc = 0.0f;
    #pragma unroll
    for (int i = 0; i < 4; ++i) {      // instr i: lanes contiguous 4KB
        float4 uv = up[i * 256 + t];
        float4 kv = kp[i * 256 + t];
        acc += uv.x * kv.x + uv.y * kv.y + uv.z * kv.z + uv.w * kv.w;
    }
    #pragma unroll
    for (int m = 32; m > 0; m >>= 1) acc += __shfl_xor(acc, m);
    if ((t & 63) == 0) partial[t >> 6] = acc;
    __syncthreads();
    if (t == 0) {
        float y = partial[0] + partial[1] + partial[2] + partial[3]
                + u_ws[(long)bh * LL + LL - 1] * Dv[h];
        float ge = 0.5f * y * (1.0f + erff(y * 0.70710678118654752f));
        g[bh] = ge;
    }
}

// k3: output projection + GLU. grid = B*128 (2 h per block), block = 256.
__global__ __launch_bounds__(256) void out_kernel(
    const float* __restrict__ g, const float* __restrict__ W,
    const float* __restrict__ bvec, float* __restrict__ out) {
    int b = blockIdx.x >> 7;
    int tile = blockIdx.x & 127;
    int t = threadIdx.x;
    int w = t >> 6, lane = t & 63;
    __shared__ float gs[HH];
    __shared__ float zb[4];
    gs[t] = g[b * HH + t];
    __syncthreads();
    int hh = tile * 2 + (w >> 1);
    int o = (w & 1) * HH + hh;
    float4 wv4 = ((const float4*)(W + o * HH))[lane];
    float4 gv4 = ((const float4*)gs)[lane];
    float p = wv4.x * gv4.x + wv4.y * gv4.y + wv4.z * gv4.z + wv4.w * gv4.w;
    #pragma unroll
    for (int m = 32; m > 0; m >>= 1) p += __shfl_xor(p, m);
    if (lane == 0) zb[w] = p + bvec[o];
    __syncthreads();
    if (t < 2) {
        int hq = tile * 2 + t;
        float z1 = zb[t * 2 + 0];
        float z2 = zb[t * 2 + 1];
        out[b * HH + hq] = z1 * (1.0f / (1.0f + expf(-z2)));
    }
}

extern "C" void kernel_launch(void* const* d_in, const int* in_sizes, int n_in,
                              void* d_out, int out_size, void* d_ws, size_t ws_size,
                              hipStream_t stream) {
    const int* input_ids = (const int*)d_in[0];
    const float* embedding = (const float*)d_in[1];
    const float* log_dt = (const float*)d_in[2];
    const float* A_log_re = (const float*)d_in[3];
    const float* A_im = (const float*)d_in[4];
    const float* B_re = (const float*)d_in[5];
    const float* B_im = (const float*)d_in[6];
    const float* C_re = (const float*)d_in[7];
    const float* C_im = (const float*)d_in[8];
    const float* D = (const float*)d_in[9];
    const float* W_out = (const float*)d_in[10];
    const float* b_out = (const float*)d_in[11];
    float* out = (float*)d_out;

    float* ws = (float*)d_ws;
    float* u_ws = ws + 327680;                    // B*H*L floats
    float* g = ws + 10813440;                     // B*H floats
    float* Krev = ws + 10815488;                  // H*L floats

    frontend_kernel<<<BB * 64 + HH, 512, 0, stream>>>(
        input_ids, embedding, log_dt, A_log_re, A_im, B_re, B_im, C_re, C_im,
        u_ws, Krev);

    conv_kernel<<<BB * HH, 256, 0, stream>>>(u_ws, Krev, D, g);

    out_kernel<<<BB * 128, 256, 0, stream>>>(g, W_out, b_out, out);
}

// Round 6
// 149.760 us; speedup vs baseline: 1.4117x; 1.4117x over previous
//
#include <hip/hip_runtime.h>
#include <math.h>

#define HH 256
#define NN 64
#define LL 4096
#define BB 8

// ws layout (floats):
//   u_ws (float [B][H][L])     @ 327680    (8388608)
//   g    (float [B][H])        @ 10813440  (2048)
//   Krev (float [H][L])        @ 10815488  (1048576)   K[h, L-1-l]

// k1: blocks [0,512) = embedding gather+transpose (unchanged, proven);
//     blocks [512,768) = K-materialization, one block per h:
//       K[h,l] = Re( sum_n w[h,n] * dA[h,n]^l ),  w = 2*C0*dB
//     wave w owns n-octet [8w,8w+8); lane owns l = j*64+lane.
//     Per-thread state is only (vr,vi,e)[8] (32 VGPRs, no kacc[64] spill):
//     at each j, s = sum_n Re(vn) -> one LDS atomicAdd; then vn *= dA_n^64.
__global__ __launch_bounds__(512) void frontend_kernel(
    const int* __restrict__ ids, const float* __restrict__ emb,
    const float* __restrict__ log_dt, const float* __restrict__ A_log_re,
    const float* __restrict__ A_im, const float* __restrict__ B_re,
    const float* __restrict__ B_im, const float* __restrict__ C_re,
    const float* __restrict__ C_im,
    float* __restrict__ u_ws, float* __restrict__ Krev) {
    __shared__ union {
        struct { int ids_s[64]; float tb[2][64][65]; } a;      // 33.5 KB
        struct { float4 cs4[NN]; float2 cs2[NN]; float Kbuf[LL]; } k; // 17.5 KB
    } sm;
    int t = threadIdx.x;
    if (blockIdx.x < BB * 64) {
        // ---------------- gather + transpose ----------------
        int b = blockIdx.x >> 6;
        int tile = blockIdx.x & 63;
        int w = t >> 6;           // wave id 0..7
        int lane = t & 63;
        int rq = lane >> 4;       // row-within-quad 0..3
        int k = lane & 15;        // float4 column 0..15
        if (t < 64) sm.a.ids_s[t] = ids[b * LL + tile * 64 + t];
        __syncthreads();
        {
            int r0 = w * 8 + rq;
            float4 v0 = *(const float4*)(emb + (long)sm.a.ids_s[r0] * HH + 4 * k);
            float4 v1 = *(const float4*)(emb + (long)sm.a.ids_s[r0 + 4] * HH + 4 * k);
            sm.a.tb[0][r0][4 * k + 0] = v0.x;
            sm.a.tb[0][r0][4 * k + 1] = v0.y;
            sm.a.tb[0][r0][4 * k + 2] = v0.z;
            sm.a.tb[0][r0][4 * k + 3] = v0.w;
            sm.a.tb[0][r0 + 4][4 * k + 0] = v1.x;
            sm.a.tb[0][r0 + 4][4 * k + 1] = v1.y;
            sm.a.tb[0][r0 + 4][4 * k + 2] = v1.z;
            sm.a.tb[0][r0 + 4][4 * k + 3] = v1.w;
        }
        __syncthreads();
        #pragma unroll
        for (int c4 = 0; c4 < 4; ++c4) {
            int cur = c4 & 1;
            float4 v0, v1;
            if (c4 < 3) {
                int r0 = w * 8 + rq;
                v0 = *(const float4*)(emb + (long)sm.a.ids_s[r0] * HH +
                                      (c4 + 1) * 64 + 4 * k);
                v1 = *(const float4*)(emb + (long)sm.a.ids_s[r0 + 4] * HH +
                                      (c4 + 1) * 64 + 4 * k);
            }
            #pragma unroll
            for (int it = 0; it < 2; ++it) {
                int hq = w * 8 + it * 4 + rq;
                int s0 = 4 * k;
                float4 o;
                o.x = sm.a.tb[cur][s0 + 0][hq];
                o.y = sm.a.tb[cur][s0 + 1][hq];
                o.z = sm.a.tb[cur][s0 + 2][hq];
                o.w = sm.a.tb[cur][s0 + 3][hq];
                *(float4*)(u_ws + ((long)(b * HH + c4 * 64 + hq)) * LL +
                           tile * 64 + s0) = o;
            }
            if (c4 < 3) {
                int r0 = w * 8 + rq;
                sm.a.tb[cur ^ 1][r0][4 * k + 0] = v0.x;
                sm.a.tb[cur ^ 1][r0][4 * k + 1] = v0.y;
                sm.a.tb[cur ^ 1][r0][4 * k + 2] = v0.z;
                sm.a.tb[cur ^ 1][r0][4 * k + 3] = v0.w;
                sm.a.tb[cur ^ 1][r0 + 4][4 * k + 0] = v1.x;
                sm.a.tb[cur ^ 1][r0 + 4][4 * k + 1] = v1.y;
                sm.a.tb[cur ^ 1][r0 + 4][4 * k + 2] = v1.z;
                sm.a.tb[cur ^ 1][r0 + 4][4 * k + 3] = v1.w;
            }
            __syncthreads();
        }
    } else {
        // ---------------- K-materialization (one block per h) ----------------
        int h = blockIdx.x - BB * 64;
        int w = t >> 6, lane = t & 63;
        #pragma unroll
        for (int i = 0; i < 8; ++i) sm.k.Kbuf[i * 512 + t] = 0.0f;
        if (t < NN) {
            int n = t;
            int idx = h * NN + n;
            float dt = expf(log_dt[h]);
            float Are = -expf(A_log_re[idx]);
            float Aim = A_im[idx];
            float ea = expf(dt * Are);
            float sn, cs;
            sincosf(dt * Aim, &sn, &cs);
            float dAre = ea * cs, dAim = ea * sn;
            float numre = dAre - 1.0f, numim = dAim;
            float den = Are * Are + Aim * Aim;
            float qre = (numre * Are + numim * Aim) / den;
            float qim = (numim * Are - numre * Aim) / den;
            float bre = B_re[idx], bim = B_im[idx];
            float dBre = bre * qre - bim * qim;
            float dBim = bre * qim + bim * qre;
            float cre = C_re[idx], cim = C_im[idx];
            float wre = 2.0f * (cre * dBre - cim * dBim);
            float wim = 2.0f * (cre * dBim + cim * dBre);
            // dA64 = dA^64
            float pr = dAre, pi = dAim;
            #pragma unroll
            for (int kq = 0; kq < 6; ++kq) {
                float nr = pr * pr - pi * pi;
                pi = 2.0f * pr * pi; pr = nr;
            }
            sm.k.cs4[n] = make_float4(dAre, dAim, wre, wim);
            sm.k.cs2[n] = make_float2(pr, pi);
        }
        __syncthreads();
        // per-n running state: vn = w_n * dA_n^(j*64+lane); en = dA_n^64
        float vr[8], vi[8], er[8], ei[8];
        #pragma unroll
        for (int nn = 0; nn < 8; ++nn) {
            int n = w * 8 + nn;
            float4 c4 = sm.k.cs4[n];     // (dAre, dAim, wre, wim) broadcast
            float2 c2 = sm.k.cs2[n];     // dA^64
            er[nn] = c2.x; ei[nn] = c2.y;
            // p = dA^lane via 6-bit square-and-multiply
            float pr = 1.0f, pi = 0.0f, br = c4.x, bi = c4.y;
            #pragma unroll
            for (int bit = 0; bit < 6; ++bit) {
                bool on = (lane >> bit) & 1;
                float mr = on ? br : 1.0f;
                float mi = on ? bi : 0.0f;
                float tr = pr * mr - pi * mi;
                pi = pr * mi + pi * mr; pr = tr;
                float t2 = br * br - bi * bi;
                bi = 2.0f * br * bi; br = t2;
            }
            vr[nn] = c4.z * pr - c4.w * pi;
            vi[nn] = c4.z * pi + c4.w * pr;
        }
        #pragma unroll 8
        for (int j = 0; j < 64; ++j) {
            float s = ((vr[0] + vr[1]) + (vr[2] + vr[3]))
                    + ((vr[4] + vr[5]) + (vr[6] + vr[7]));
            atomicAdd(&sm.k.Kbuf[j * 64 + lane], s);
            #pragma unroll
            for (int nn = 0; nn < 8; ++nn) {
                float tr = vr[nn] * er[nn] - vi[nn] * ei[nn];
                vi[nn] = vr[nn] * ei[nn] + vi[nn] * er[nn];
                vr[nn] = tr;
            }
        }
        __syncthreads();
        #pragma unroll
        for (int i = 0; i < 8; ++i) {
            int tp = i * 512 + t;
            Krev[h * LL + tp] = sm.k.Kbuf[LL - 1 - tp];   // store reversed
        }
    }
}

// k2: conv -- y[b,h] = sum_t u[t]*Krev[t] + D[h]*u[L-1], GELU -> g.
// Pure streaming dot: 2048 blocks x 256 threads, 16 floats per thread.
__global__ __launch_bounds__(256) void conv_kernel(
    const float* __restrict__ u_ws, const float* __restrict__ Krev,
    const float* __restrict__ Dv, float* __restrict__ g) {
    __shared__ float partial[4];
    int t = threadIdx.x;
    int bh = blockIdx.x;
    int h = bh & (HH - 1);
    const float4* up = (const float4*)(u_ws + (long)bh * LL);
    const float4* kp = (const float4*)(Krev + h * LL);
    float acc = 0.0f;
    #pragma unroll
    for (int i = 0; i < 4; ++i) {      // instr i: lanes contiguous 4KB
        float4 uv = up[i * 256 + t];
        float4 kv = kp[i * 256 + t];
        acc += uv.x * kv.x + uv.y * kv.y + uv.z * kv.z + uv.w * kv.w;
    }
    #pragma unroll
    for (int m = 32; m > 0; m >>= 1) acc += __shfl_xor(acc, m);
    if ((t & 63) == 0) partial[t >> 6] = acc;
    __syncthreads();
    if (t == 0) {
        float y = partial[0] + partial[1] + partial[2] + partial[3]
                + u_ws[(long)bh * LL + LL - 1] * Dv[h];
        float ge = 0.5f * y * (1.0f + erff(y * 0.70710678118654752f));
        g[bh] = ge;
    }
}

// k3: output projection + GLU. grid = B*128 (2 h per block), block = 256.
__global__ __launch_bounds__(256) void out_kernel(
    const float* __restrict__ g, const float* __restrict__ W,
    const float* __restrict__ bvec, float* __restrict__ out) {
    int b = blockIdx.x >> 7;
    int tile = blockIdx.x & 127;
    int t = threadIdx.x;
    int w = t >> 6, lane = t & 63;
    __shared__ float gs[HH];
    __shared__ float zb[4];
    gs[t] = g[b * HH + t];
    __syncthreads();
    int hh = tile * 2 + (w >> 1);
    int o = (w & 1) * HH + hh;
    float4 wv4 = ((const float4*)(W + o * HH))[lane];
    float4 gv4 = ((const float4*)gs)[lane];
    float p = wv4.x * gv4.x + wv4.y * gv4.y + wv4.z * gv4.z + wv4.w * gv4.w;
    #pragma unroll
    for (int m = 32; m > 0; m >>= 1) p += __shfl_xor(p, m);
    if (lane == 0) zb[w] = p + bvec[o];
    __syncthreads();
    if (t < 2) {
        int hq = tile * 2 + t;
        float z1 = zb[t * 2 + 0];
        float z2 = zb[t * 2 + 1];
        out[b * HH + hq] = z1 * (1.0f / (1.0f + expf(-z2)));
    }
}

extern "C" void kernel_launch(void* const* d_in, const int* in_sizes, int n_in,
                              void* d_out, int out_size, void* d_ws, size_t ws_size,
                              hipStream_t stream) {
    const int* input_ids = (const int*)d_in[0];
    const float* embedding = (const float*)d_in[1];
    const float* log_dt = (const float*)d_in[2];
    const float* A_log_re = (const float*)d_in[3];
    const float* A_im = (const float*)d_in[4];
    const float* B_re = (const float*)d_in[5];
    const float* B_im = (const float*)d_in[6];
    const float* C_re = (const float*)d_in[7];
    const float* C_im = (const float*)d_in[8];
    const float* D = (const float*)d_in[9];
    const float* W_out = (const float*)d_in[10];
    const float* b_out = (const float*)d_in[11];
    float* out = (float*)d_out;

    float* ws = (float*)d_ws;
    float* u_ws = ws + 327680;                    // B*H*L floats
    float* g = ws + 10813440;                     // B*H floats
    float* Krev = ws + 10815488;                  // H*L floats

    frontend_kernel<<<BB * 64 + HH, 512, 0, stream>>>(
        input_ids, embedding, log_dt, A_log_re, A_im, B_re, B_im, C_re, C_im,
        u_ws, Krev);

    conv_kernel<<<BB * HH, 256, 0, stream>>>(u_ws, Krev, D, g);

    out_kernel<<<BB * 128, 256, 0, stream>>>(g, W_out, b_out, out);
}

// Round 7
// 119.472 us; speedup vs baseline: 1.7696x; 1.2535x over previous
//
#include <hip/hip_runtime.h>
#include <math.h>

#define HH 256
#define NN 64
#define LL 4096
#define BB 8

// ws layout (floats):
//   u_ws (float [B][H][L])     @ 327680    (8388608)
//   g    (float [B][H])        @ 10813440  (2048)
//   Krev (float [H][L])        @ 10815488  (1048576)   K[h, L-1-l]

// k1: blocks [0,512) = embedding gather+transpose (unchanged, proven);
//     blocks [512,768) = K-materialization, one block per h:
//       K[h,l] = Re( sum_n w[h,n] * dA[h,n]^l ),  w = 2*C0*dB
//     NEW decomposition: wave w owns l-range [512w,512w+512), lane owns
//     l%64, n is SERIAL per thread -> each l owned by exactly one thread:
//     no atomics, no cross-thread merge, live state = kacc[8]+v (~20 VGPR).
//     dA_n^lane comes from a padded LDS table powR/powI[64][65] (bank =
//     (lane+n)%32, conflict-free); per-n constants are uniform broadcasts.
__global__ __launch_bounds__(512) void frontend_kernel(
    const int* __restrict__ ids, const float* __restrict__ emb,
    const float* __restrict__ log_dt, const float* __restrict__ A_log_re,
    const float* __restrict__ A_im, const float* __restrict__ B_re,
    const float* __restrict__ B_im, const float* __restrict__ C_re,
    const float* __restrict__ C_im,
    float* __restrict__ u_ws, float* __restrict__ Krev) {
    __shared__ union {
        struct { int ids_s[64]; float tb[2][64][65]; } a;     // 33.5 KB
        struct { float powR[64][65]; float powI[64][65];      // 33.3 KB
                 float2 dAt[64]; float2 e64t[64]; float2 W2[8][64]; } k; // +5.1 KB
    } sm;
    int t = threadIdx.x;
    if (blockIdx.x < BB * 64) {
        // ---------------- gather + transpose ----------------
        int b = blockIdx.x >> 6;
        int tile = blockIdx.x & 63;
        int w = t >> 6;           // wave id 0..7
        int lane = t & 63;
        int rq = lane >> 4;       // row-within-quad 0..3
        int k = lane & 15;        // float4 column 0..15
        if (t < 64) sm.a.ids_s[t] = ids[b * LL + tile * 64 + t];
        __syncthreads();
        {
            int r0 = w * 8 + rq;
            float4 v0 = *(const float4*)(emb + (long)sm.a.ids_s[r0] * HH + 4 * k);
            float4 v1 = *(const float4*)(emb + (long)sm.a.ids_s[r0 + 4] * HH + 4 * k);
            sm.a.tb[0][r0][4 * k + 0] = v0.x;
            sm.a.tb[0][r0][4 * k + 1] = v0.y;
            sm.a.tb[0][r0][4 * k + 2] = v0.z;
            sm.a.tb[0][r0][4 * k + 3] = v0.w;
            sm.a.tb[0][r0 + 4][4 * k + 0] = v1.x;
            sm.a.tb[0][r0 + 4][4 * k + 1] = v1.y;
            sm.a.tb[0][r0 + 4][4 * k + 2] = v1.z;
            sm.a.tb[0][r0 + 4][4 * k + 3] = v1.w;
        }
        __syncthreads();
        #pragma unroll
        for (int c4 = 0; c4 < 4; ++c4) {
            int cur = c4 & 1;
            float4 v0, v1;
            if (c4 < 3) {
                int r0 = w * 8 + rq;
                v0 = *(const float4*)(emb + (long)sm.a.ids_s[r0] * HH +
                                      (c4 + 1) * 64 + 4 * k);
                v1 = *(const float4*)(emb + (long)sm.a.ids_s[r0 + 4] * HH +
                                      (c4 + 1) * 64 + 4 * k);
            }
            #pragma unroll
            for (int it = 0; it < 2; ++it) {
                int hq = w * 8 + it * 4 + rq;
                int s0 = 4 * k;
                float4 o;
                o.x = sm.a.tb[cur][s0 + 0][hq];
                o.y = sm.a.tb[cur][s0 + 1][hq];
                o.z = sm.a.tb[cur][s0 + 2][hq];
                o.w = sm.a.tb[cur][s0 + 3][hq];
                *(float4*)(u_ws + ((long)(b * HH + c4 * 64 + hq)) * LL +
                           tile * 64 + s0) = o;
            }
            if (c4 < 3) {
                int r0 = w * 8 + rq;
                sm.a.tb[cur ^ 1][r0][4 * k + 0] = v0.x;
                sm.a.tb[cur ^ 1][r0][4 * k + 1] = v0.y;
                sm.a.tb[cur ^ 1][r0][4 * k + 2] = v0.z;
                sm.a.tb[cur ^ 1][r0][4 * k + 3] = v0.w;
                sm.a.tb[cur ^ 1][r0 + 4][4 * k + 0] = v1.x;
                sm.a.tb[cur ^ 1][r0 + 4][4 * k + 1] = v1.y;
                sm.a.tb[cur ^ 1][r0 + 4][4 * k + 2] = v1.z;
                sm.a.tb[cur ^ 1][r0 + 4][4 * k + 3] = v1.w;
            }
            __syncthreads();
        }
    } else {
        // ---------------- K-materialization (one block per h) ----------------
        int h = blockIdx.x - BB * 64;
        int w = __builtin_amdgcn_readfirstlane(t >> 6);   // wave id 0..7
        int lane = t & 63;
        // -- stage 1 (wave 0): per-n constants --
        if (t < NN) {
            int n = t;
            int idx = h * NN + n;
            float dt = expf(log_dt[h]);
            float Are = -expf(A_log_re[idx]);
            float Aim = A_im[idx];
            float ea = expf(dt * Are);
            float sn, cs;
            sincosf(dt * Aim, &sn, &cs);
            float dAre = ea * cs, dAim = ea * sn;
            float numre = dAre - 1.0f, numim = dAim;
            float den = Are * Are + Aim * Aim;
            float qre = (numre * Are + numim * Aim) / den;
            float qim = (numim * Are - numre * Aim) / den;
            float bre = B_re[idx], bim = B_im[idx];
            float dBre = bre * qre - bim * qim;
            float dBim = bre * qim + bim * qre;
            float cre = C_re[idx], cim = C_im[idx];
            float wre = 2.0f * (cre * dBre - cim * dBim);
            float wim = 2.0f * (cre * dBim + cim * dBre);
            sm.k.dAt[n] = make_float2(dAre, dAim);
            // e64 = dA^64 (6 squarings)
            float pr = dAre, pi = dAim;
            #pragma unroll
            for (int kq = 0; kq < 6; ++kq) {
                float nr = pr * pr - pi * pi;
                pi = 2.0f * pr * pi; pr = nr;
            }
            sm.k.e64t[n] = make_float2(pr, pi);
            // dA^512 = 3 more squarings
            #pragma unroll
            for (int kq = 0; kq < 3; ++kq) {
                float nr = pr * pr - pi * pi;
                pi = 2.0f * pr * pi; pr = nr;
            }
            // W2[k][n] = w_n * dA^(512k)
            float qr2 = wre, qi2 = wim;
            #pragma unroll
            for (int kk = 0; kk < 8; ++kk) {
                sm.k.W2[kk][n] = make_float2(qr2, qi2);
                float nr = qr2 * pr - qi2 * pi, ni = qr2 * pi + qi2 * pr;
                qr2 = nr; qi2 = ni;
            }
        }
        __syncthreads();
        // -- stage 2 (all waves): pow table, wave w covers m = 8w..8w+7 --
        {
            float2 a = sm.k.dAt[lane];             // dA_n, n = lane
            // d8 = dA^8 (3 squarings)
            float br = a.x, bi = a.y;
            #pragma unroll
            for (int kq = 0; kq < 3; ++kq) {
                float nr = br * br - bi * bi;
                bi = 2.0f * br * bi; br = nr;
            }
            // start = d8^w (w wave-uniform, 3-bit square-multiply)
            float pr = 1.0f, pi = 0.0f;
            #pragma unroll
            for (int bit = 0; bit < 3; ++bit) {
                if ((w >> bit) & 1) {
                    float tr = pr * br - pi * bi;
                    pi = pr * bi + pi * br; pr = tr;
                }
                float t2 = br * br - bi * bi;
                bi = 2.0f * br * bi; br = t2;
            }
            // pow[8w+i][n] = dA_n^(8w+i)
            #pragma unroll
            for (int i = 0; i < 8; ++i) {
                sm.k.powR[8 * w + i][lane] = pr;
                sm.k.powI[8 * w + i][lane] = pi;
                float tr = pr * a.x - pi * a.y;
                pi = pr * a.y + pi * a.x; pr = tr;
            }
        }
        __syncthreads();
        // -- stage 3: main accumulation; thread owns l = 512w + 64j + lane --
        float kacc[8];
        #pragma unroll
        for (int j = 0; j < 8; ++j) kacc[j] = 0.0f;
        #pragma unroll 2
        for (int n = 0; n < NN; ++n) {
            float Pr = sm.k.powR[lane][n];         // dA_n^lane, conflict-free
            float Pi = sm.k.powI[lane][n];
            float2 E = sm.k.e64t[n];               // uniform broadcast
            float2 Wn = sm.k.W2[w][n];             // uniform broadcast
            float vr = Wn.x * Pr - Wn.y * Pi;      // v = w_n*dA^(512w)*dA^lane
            float vi = Wn.x * Pi + Wn.y * Pr;
            #pragma unroll
            for (int j = 0; j < 8; ++j) {
                kacc[j] += vr;
                float tr = vr * E.x - vi * E.y;
                vi = vr * E.y + vi * E.x; vr = tr;
            }
        }
        // -- store reversed: Krev[h][L-1-l] = K[h][l] --
        #pragma unroll
        for (int j = 0; j < 8; ++j) {
            int l = w * 512 + j * 64 + lane;
            Krev[h * LL + (LL - 1 - l)] = kacc[j];
        }
    }
}

// k2: conv -- y[b,h] = sum_t u[t]*Krev[t] + D[h]*u[L-1], GELU -> g.
// Pure streaming dot: 2048 blocks x 256 threads, 16 floats per thread.
__global__ __launch_bounds__(256) void conv_kernel(
    const float* __restrict__ u_ws, const float* __restrict__ Krev,
    const float* __restrict__ Dv, float* __restrict__ g) {
    __shared__ float partial[4];
    int t = threadIdx.x;
    int bh = blockIdx.x;
    int h = bh & (HH - 1);
    const float4* up = (const float4*)(u_ws + (long)bh * LL);
    const float4* kp = (const float4*)(Krev + h * LL);
    float acc = 0.0f;
    #pragma unroll
    for (int i = 0; i < 4; ++i) {      // instr i: lanes contiguous 4KB
        float4 uv = up[i * 256 + t];
        float4 kv = kp[i * 256 + t];
        acc += uv.x * kv.x + uv.y * kv.y + uv.z * kv.z + uv.w * kv.w;
    }
    #pragma unroll
    for (int m = 32; m > 0; m >>= 1) acc += __shfl_xor(acc, m);
    if ((t & 63) == 0) partial[t >> 6] = acc;
    __syncthreads();
    if (t == 0) {
        float y = partial[0] + partial[1] + partial[2] + partial[3]
                + u_ws[(long)bh * LL + LL - 1] * Dv[h];
        float ge = 0.5f * y * (1.0f + erff(y * 0.70710678118654752f));
        g[bh] = ge;
    }
}

// k3: output projection + GLU. grid = B*128 (2 h per block), block = 256.
__global__ __launch_bounds__(256) void out_kernel(
    const float* __restrict__ g, const float* __restrict__ W,
    const float* __restrict__ bvec, float* __restrict__ out) {
    int b = blockIdx.x >> 7;
    int tile = blockIdx.x & 127;
    int t = threadIdx.x;
    int w = t >> 6, lane = t & 63;
    __shared__ float gs[HH];
    __shared__ float zb[4];
    gs[t] = g[b * HH + t];
    __syncthreads();
    int hh = tile * 2 + (w >> 1);
    int o = (w & 1) * HH + hh;
    float4 wv4 = ((const float4*)(W + o * HH))[lane];
    float4 gv4 = ((const float4*)gs)[lane];
    float p = wv4.x * gv4.x + wv4.y * gv4.y + wv4.z * gv4.z + wv4.w * gv4.w;
    #pragma unroll
    for (int m = 32; m > 0; m >>= 1) p += __shfl_xor(p, m);
    if (lane == 0) zb[w] = p + bvec[o];
    __syncthreads();
    if (t < 2) {
        int hq = tile * 2 + t;
        float z1 = zb[t * 2 + 0];
        float z2 = zb[t * 2 + 1];
        out[b * HH + hq] = z1 * (1.0f / (1.0f + expf(-z2)));
    }
}

extern "C" void kernel_launch(void* const* d_in, const int* in_sizes, int n_in,
                              void* d_out, int out_size, void* d_ws, size_t ws_size,
                              hipStream_t stream) {
    const int* input_ids = (const int*)d_in[0];
    const float* embedding = (const float*)d_in[1];
    const float* log_dt = (const float*)d_in[2];
    const float* A_log_re = (const float*)d_in[3];
    const float* A_im = (const float*)d_in[4];
    const float* B_re = (const float*)d_in[5];
    const float* B_im = (const float*)d_in[6];
    const float* C_re = (const float*)d_in[7];
    const float* C_im = (const float*)d_in[8];
    const float* D = (const float*)d_in[9];
    const float* W_out = (const float*)d_in[10];
    const float* b_out = (const float*)d_in[11];
    float* out = (float*)d_out;

    float* ws = (float*)d_ws;
    float* u_ws = ws + 327680;                    // B*H*L floats
    float* g = ws + 10813440;                     // B*H floats
    float* Krev = ws + 10815488;                  // H*L floats

    frontend_kernel<<<BB * 64 + HH, 512, 0, stream>>>(
        input_ids, embedding, log_dt, A_log_re, A_im, B_re, B_im, C_re, C_im,
        u_ws, Krev);

    conv_kernel<<<BB * HH, 256, 0, stream>>>(u_ws, Krev, D, g);

    out_kernel<<<BB * 128, 256, 0, stream>>>(g, W_out, b_out, out);
}